// Round 1
// baseline (1857.932 us; speedup 1.0000x reference)
//
#include <hip/hip_runtime.h>

#define N_NODES 50000
#define E_EDGES 800000
#define D_INF   128
#define D_HIDF  512
#define D_OUTF  128

// ---------------- scatter: v_agg[dst] += w * v[src] ----------------
// 32 threads per edge, float4 per thread (32*4 = 128 features)
__global__ void scatter_add_kernel(const float* __restrict__ v,
                                   const int* __restrict__ src,
                                   const int* __restrict__ dst,
                                   const float* __restrict__ w,
                                   float* __restrict__ vagg) {
    long long gid = (long long)blockIdx.x * blockDim.x + threadIdx.x;
    int e = (int)(gid >> 5);
    if (e >= E_EDGES) return;
    int c = (int)(gid & 31) << 2;
    int s = src[e];
    int d = dst[e];
    float we = w[e];
    const float4 vv = *(const float4*)(v + (size_t)s * D_INF + c);
    float* out = vagg + (size_t)d * D_INF + c;
    atomicAdd(out + 0, vv.x * we);
    atomicAdd(out + 1, vv.y * we);
    atomicAdd(out + 2, vv.z * we);
    atomicAdd(out + 3, vv.w * we);
}

// ---------------- v_agg += epsilon * v ----------------
__global__ void eps_add_kernel(float* __restrict__ vagg,
                               const float* __restrict__ v,
                               const float* __restrict__ eps_p, int n4) {
    int i = blockIdx.x * blockDim.x + threadIdx.x;
    if (i >= n4) return;
    float e = eps_p[0];
    float4 a = ((float4*)vagg)[i];
    float4 b = ((const float4*)v)[i];
    a.x += e * b.x; a.y += e * b.y; a.z += e * b.z; a.w += e * b.w;
    ((float4*)vagg)[i] = a;
}

// ---------------- tiled fp32 GEMM + bias: C[M,Ncols] = A[M,K]*B[K,Ncols]+bias ----------------
// 64x64 tile, BK=16, 256 threads, 4x4 accum per thread
__global__ __launch_bounds__(256) void gemm_bias_kernel(
        const float* __restrict__ A, const float* __restrict__ B,
        const float* __restrict__ bias, float* __restrict__ C,
        int M, int Ncols, int K) {
    __shared__ float As[16][65];   // +1 pad: transposed stores
    __shared__ float Bs[16][64];
    const int bm = blockIdx.y * 64;
    const int bn = blockIdx.x * 64;
    const int tid = threadIdx.x;
    const int tx = tid & 15;       // col group
    const int ty = tid >> 4;       // row group
    float acc[4][4] = {};

    for (int k0 = 0; k0 < K; k0 += 16) {
        // A tile: 64 rows x 16 cols, store transposed As[k][m]
        {
            int r = tid >> 2;              // 0..63
            int c = (tid & 3) << 2;        // 0,4,8,12
            int row = bm + r;
            float4 a = make_float4(0.f, 0.f, 0.f, 0.f);
            if (row < M) a = *(const float4*)(A + (size_t)row * K + k0 + c);
            As[c + 0][r] = a.x;
            As[c + 1][r] = a.y;
            As[c + 2][r] = a.z;
            As[c + 3][r] = a.w;
        }
        // B tile: 16 rows x 64 cols
        {
            int r = tid >> 4;              // 0..15
            int c = (tid & 15) << 2;       // 0..60
            float4 b = *(const float4*)(B + (size_t)(k0 + r) * Ncols + bn + c);
            *(float4*)&Bs[r][c] = b;
        }
        __syncthreads();
#pragma unroll
        for (int k = 0; k < 16; ++k) {
            float a0 = As[k][ty * 4 + 0];
            float a1 = As[k][ty * 4 + 1];
            float a2 = As[k][ty * 4 + 2];
            float a3 = As[k][ty * 4 + 3];
            float b0 = Bs[k][tx * 4 + 0];
            float b1 = Bs[k][tx * 4 + 1];
            float b2 = Bs[k][tx * 4 + 2];
            float b3 = Bs[k][tx * 4 + 3];
            acc[0][0] += a0 * b0; acc[0][1] += a0 * b1; acc[0][2] += a0 * b2; acc[0][3] += a0 * b3;
            acc[1][0] += a1 * b0; acc[1][1] += a1 * b1; acc[1][2] += a1 * b2; acc[1][3] += a1 * b3;
            acc[2][0] += a2 * b0; acc[2][1] += a2 * b1; acc[2][2] += a2 * b2; acc[2][3] += a2 * b3;
            acc[3][0] += a3 * b0; acc[3][1] += a3 * b1; acc[3][2] += a3 * b2; acc[3][3] += a3 * b3;
        }
        __syncthreads();
    }

    const float4 bb = *(const float4*)(bias + bn + tx * 4);
#pragma unroll
    for (int i = 0; i < 4; ++i) {
        int row = bm + ty * 4 + i;
        if (row < M) {
            float4 o;
            o.x = acc[i][0] + bb.x;
            o.y = acc[i][1] + bb.y;
            o.z = acc[i][2] + bb.z;
            o.w = acc[i][3] + bb.w;
            *(float4*)(C + (size_t)row * Ncols + bn + tx * 4) = o;
        }
    }
}

// ---------------- BN stats: per-column sum & sumsq ----------------
// blockDim.x == C (128 or 512); each block handles a chunk of rows, coalesced row reads
__global__ void bn_stats_kernel(const float* __restrict__ X,
                                float* __restrict__ sum, float* __restrict__ sumsq,
                                int n_rows, int C, int rows_per_block) {
    int c = threadIdx.x;
    int r0 = blockIdx.x * rows_per_block;
    int r1 = r0 + rows_per_block;
    if (r1 > n_rows) r1 = n_rows;
    float s = 0.f, q = 0.f;
    for (int r = r0; r < r1; ++r) {
        float x = X[(size_t)r * C + c];
        s += x;
        q += x * x;
    }
    atomicAdd(&sum[c], s);
    atomicAdd(&sumsq[c], q);
}

// ---------------- BN finalize: fold gamma/beta/mean/rstd -> scale/shift ----------------
__global__ void bn_finalize_kernel(const float* __restrict__ sum, const float* __restrict__ sumsq,
                                   const float* __restrict__ gamma, const float* __restrict__ beta,
                                   float* __restrict__ scale, float* __restrict__ shift,
                                   float inv_n) {
    int c = threadIdx.x;
    float m = sum[c] * inv_n;
    float var = sumsq[c] * inv_n - m * m;
    float rs = rsqrtf(var + 1e-5f);
    float sc = gamma[c] * rs;
    scale[c] = sc;
    shift[c] = beta[c] - sc * m;
}

// ---------------- BN apply + ReLU (in-place capable) ----------------
__global__ void bn_apply_relu_kernel(const float* __restrict__ X, float* __restrict__ Y,
                                     const float* __restrict__ scale,
                                     const float* __restrict__ shift,
                                     int n4, int c4mask) {
    int i = blockIdx.x * blockDim.x + threadIdx.x;
    if (i >= n4) return;
    int c = (i & c4mask) << 2;
    float4 x = ((const float4*)X)[i];
    float4 sc = *(const float4*)(scale + c);
    float4 sh = *(const float4*)(shift + c);
    float4 y;
    y.x = fmaxf(0.f, x.x * sc.x + sh.x);
    y.y = fmaxf(0.f, x.y * sc.y + sh.y);
    y.z = fmaxf(0.f, x.z * sc.z + sh.z);
    y.w = fmaxf(0.f, x.w * sc.w + sh.w);
    ((float4*)Y)[i] = y;
}

extern "C" void kernel_launch(void* const* d_in, const int* in_sizes, int n_in,
                              void* d_out, int out_size, void* d_ws, size_t ws_size,
                              hipStream_t stream) {
    const float* v    = (const float*)d_in[0];
    const int* src    = (const int*)d_in[1];
    const int* dst    = (const int*)d_in[2];
    const float* ew   = (const float*)d_in[3];
    const float* eps  = (const float*)d_in[4];
    const float* W1   = (const float*)d_in[5];
    const float* b1   = (const float*)d_in[6];
    const float* g1   = (const float*)d_in[7];
    const float* be1  = (const float*)d_in[8];
    const float* W2   = (const float*)d_in[9];
    const float* b2   = (const float*)d_in[10];
    const float* g2   = (const float*)d_in[11];
    const float* be2  = (const float*)d_in[12];
    float* out = (float*)d_out;

    // workspace layout (floats)
    float* ws = (float*)d_ws;
    float* vagg   = ws;                                   // N*128 = 6,400,000
    float* sum1   = ws + 6400000;                         // 512
    float* sumsq1 = sum1 + 512;                           // 512
    float* sum2   = sumsq1 + 512;                         // 128
    float* sumsq2 = sum2 + 128;                           // 128
    float* scale1 = sumsq2 + 128;                         // 512
    float* shift1 = scale1 + 512;                         // 512
    float* scale2 = shift1 + 512;                         // 128
    float* shift2 = scale2 + 128;                         // 128
    float* x1     = ws + 6400000 + 2560;                  // N*512 = 25,600,000

    // zero v_agg + stat accumulators (covers sums; scale/shift are fully written)
    hipMemsetAsync(d_ws, 0, (size_t)(6400000 + 2560) * sizeof(float), stream);

    // 1) scatter aggregate
    {
        long long total = (long long)E_EDGES * 32;
        int blocks = (int)((total + 255) / 256);
        scatter_add_kernel<<<blocks, 256, 0, stream>>>(v, src, dst, ew, vagg);
    }
    // 2) epsilon residual
    {
        int n4 = N_NODES * D_INF / 4;
        eps_add_kernel<<<(n4 + 255) / 256, 256, 0, stream>>>(vagg, v, eps, n4);
    }
    // 3) GEMM1: x1 = vagg @ W1 + b1   [50000,128]x[128,512]
    {
        dim3 grid(D_HIDF / 64, (N_NODES + 63) / 64);
        gemm_bias_kernel<<<grid, 256, 0, stream>>>(vagg, W1, b1, x1, N_NODES, D_HIDF, D_INF);
    }
    // 4) BN1 stats + finalize + apply(ReLU) in-place
    {
        int rpb = 256;
        int blocks = (N_NODES + rpb - 1) / rpb;
        bn_stats_kernel<<<blocks, D_HIDF, 0, stream>>>(x1, sum1, sumsq1, N_NODES, D_HIDF, rpb);
        bn_finalize_kernel<<<1, D_HIDF, 0, stream>>>(sum1, sumsq1, g1, be1, scale1, shift1, 1.0f / N_NODES);
        int n4 = N_NODES * D_HIDF / 4;
        bn_apply_relu_kernel<<<(n4 + 255) / 256, 256, 0, stream>>>(x1, x1, scale1, shift1, n4, 127);
    }
    // 5) GEMM2: out = h @ W2 + b2   [50000,512]x[512,128]
    {
        dim3 grid(D_OUTF / 64, (N_NODES + 63) / 64);
        gemm_bias_kernel<<<grid, 256, 0, stream>>>(x1, W2, b2, out, N_NODES, D_OUTF, D_HIDF);
    }
    // 6) BN2 stats + finalize + apply(ReLU) in-place on d_out
    {
        int rpb = 256;
        int blocks = (N_NODES + rpb - 1) / rpb;
        bn_stats_kernel<<<blocks, D_OUTF, 0, stream>>>(out, sum2, sumsq2, N_NODES, D_OUTF, rpb);
        bn_finalize_kernel<<<1, D_OUTF, 0, stream>>>(sum2, sumsq2, g2, be2, scale2, shift2, 1.0f / N_NODES);
        int n4 = N_NODES * D_OUTF / 4;
        bn_apply_relu_kernel<<<(n4 + 255) / 256, 256, 0, stream>>>(out, out, scale2, shift2, n4, 31);
    }
}

// Round 2
// 727.942 us; speedup vs baseline: 2.5523x; 2.5523x over previous
//
#include <hip/hip_runtime.h>

#define N_NODES 50000
#define E_EDGES 800000
#define D_INF   128
#define D_HIDF  512
#define D_OUTF  128

// ---------------- CSR build step 1: histogram of dst ----------------
__global__ void hist_kernel(const int* __restrict__ dst, int* __restrict__ counts) {
    int e = blockIdx.x * blockDim.x + threadIdx.x;
    if (e >= E_EDGES) return;
    atomicAdd(&counts[dst[e]], 1);
}

// ---------------- CSR build step 2: exclusive scan (single block) ----------------
__global__ __launch_bounds__(1024) void scan_kernel(const int* __restrict__ counts,
                                                    int* __restrict__ row_start) {
    __shared__ int partial[1024];
    const int tid = threadIdx.x;
    const int CH = (N_NODES + 1023) / 1024;   // 49
    const int base = tid * CH;
    int s = 0;
    for (int i = 0; i < CH; ++i) {
        int idx = base + i;
        if (idx < N_NODES) s += counts[idx];
    }
    partial[tid] = s;
    __syncthreads();
    // Hillis-Steele inclusive scan over 1024 partials
    for (int off = 1; off < 1024; off <<= 1) {
        int v = (tid >= off) ? partial[tid - off] : 0;
        __syncthreads();
        partial[tid] += v;
        __syncthreads();
    }
    int prefix = (tid == 0) ? 0 : partial[tid - 1];
    for (int i = 0; i < CH; ++i) {
        int idx = base + i;
        if (idx < N_NODES) {
            row_start[idx] = prefix;
            prefix += counts[idx];
        }
    }
    if (tid == 1023) row_start[N_NODES] = prefix;   // == E_EDGES
}

// ---------------- CSR build step 3: fill src/weight per dst bucket ----------------
__global__ void fill_kernel(const int* __restrict__ src, const int* __restrict__ dst,
                            const float* __restrict__ w,
                            const int* __restrict__ row_start, int* __restrict__ cursor,
                            int* __restrict__ csr_src, float* __restrict__ csr_w) {
    int e = blockIdx.x * blockDim.x + threadIdx.x;
    if (e >= E_EDGES) return;
    int d = dst[e];
    int pos = atomicAdd(&cursor[d], 1);
    int idx = row_start[d] + pos;
    csr_src[idx] = src[e];
    csr_w[idx]   = w[e];
}

// ---------------- gather: vagg[n] = sum_j w_j * v[src_j] + eps * v[n] ----------------
// 32 lanes per node, float4 per lane (32*4 = 128 features); neighbor row reads are
// contiguous 512B per edge; v (25.6 MB) is L3-resident.
__global__ __launch_bounds__(256) void gather_kernel(const float* __restrict__ v,
                                                     const int* __restrict__ row_start,
                                                     const int* __restrict__ csr_src,
                                                     const float* __restrict__ csr_w,
                                                     const float* __restrict__ eps_p,
                                                     float* __restrict__ vagg) {
    int node = blockIdx.x * 8 + (threadIdx.x >> 5);
    if (node >= N_NODES) return;
    int lane4 = (threadIdx.x & 31) << 2;
    int beg = row_start[node];
    int end = row_start[node + 1];
    float ax = 0.f, ay = 0.f, az = 0.f, aw = 0.f;
    for (int j = beg; j < end; ++j) {
        int s = csr_src[j];
        float we = csr_w[j];
        const float4 vv = *(const float4*)(v + (size_t)s * D_INF + lane4);
        ax += we * vv.x; ay += we * vv.y; az += we * vv.z; aw += we * vv.w;
    }
    float e = eps_p[0];
    const float4 vn = *(const float4*)(v + (size_t)node * D_INF + lane4);
    float4 o;
    o.x = ax + e * vn.x;
    o.y = ay + e * vn.y;
    o.z = az + e * vn.z;
    o.w = aw + e * vn.w;
    *(float4*)(vagg + (size_t)node * D_INF + lane4) = o;
}

// ---------------- tiled fp32 GEMM + bias: C[M,Ncols] = A[M,K]*B[K,Ncols]+bias ----------------
__global__ __launch_bounds__(256) void gemm_bias_kernel(
        const float* __restrict__ A, const float* __restrict__ B,
        const float* __restrict__ bias, float* __restrict__ C,
        int M, int Ncols, int K) {
    __shared__ float As[16][65];
    __shared__ float Bs[16][64];
    const int bm = blockIdx.y * 64;
    const int bn = blockIdx.x * 64;
    const int tid = threadIdx.x;
    const int tx = tid & 15;
    const int ty = tid >> 4;
    float acc[4][4] = {};

    for (int k0 = 0; k0 < K; k0 += 16) {
        {
            int r = tid >> 2;
            int c = (tid & 3) << 2;
            int row = bm + r;
            float4 a = make_float4(0.f, 0.f, 0.f, 0.f);
            if (row < M) a = *(const float4*)(A + (size_t)row * K + k0 + c);
            As[c + 0][r] = a.x;
            As[c + 1][r] = a.y;
            As[c + 2][r] = a.z;
            As[c + 3][r] = a.w;
        }
        {
            int r = tid >> 4;
            int c = (tid & 15) << 2;
            float4 b = *(const float4*)(B + (size_t)(k0 + r) * Ncols + bn + c);
            *(float4*)&Bs[r][c] = b;
        }
        __syncthreads();
#pragma unroll
        for (int k = 0; k < 16; ++k) {
            float a0 = As[k][ty * 4 + 0];
            float a1 = As[k][ty * 4 + 1];
            float a2 = As[k][ty * 4 + 2];
            float a3 = As[k][ty * 4 + 3];
            float b0 = Bs[k][tx * 4 + 0];
            float b1 = Bs[k][tx * 4 + 1];
            float b2 = Bs[k][tx * 4 + 2];
            float b3 = Bs[k][tx * 4 + 3];
            acc[0][0] += a0 * b0; acc[0][1] += a0 * b1; acc[0][2] += a0 * b2; acc[0][3] += a0 * b3;
            acc[1][0] += a1 * b0; acc[1][1] += a1 * b1; acc[1][2] += a1 * b2; acc[1][3] += a1 * b3;
            acc[2][0] += a2 * b0; acc[2][1] += a2 * b1; acc[2][2] += a2 * b2; acc[2][3] += a2 * b3;
            acc[3][0] += a3 * b0; acc[3][1] += a3 * b1; acc[3][2] += a3 * b2; acc[3][3] += a3 * b3;
        }
        __syncthreads();
    }

    const float4 bb = *(const float4*)(bias + bn + tx * 4);
#pragma unroll
    for (int i = 0; i < 4; ++i) {
        int row = bm + ty * 4 + i;
        if (row < M) {
            float4 o;
            o.x = acc[i][0] + bb.x;
            o.y = acc[i][1] + bb.y;
            o.z = acc[i][2] + bb.z;
            o.w = acc[i][3] + bb.w;
            *(float4*)(C + (size_t)row * Ncols + bn + tx * 4) = o;
        }
    }
}

// ---------------- BN stats ----------------
__global__ void bn_stats_kernel(const float* __restrict__ X,
                                float* __restrict__ sum, float* __restrict__ sumsq,
                                int n_rows, int C, int rows_per_block) {
    int c = threadIdx.x;
    int r0 = blockIdx.x * rows_per_block;
    int r1 = r0 + rows_per_block;
    if (r1 > n_rows) r1 = n_rows;
    float s = 0.f, q = 0.f;
    for (int r = r0; r < r1; ++r) {
        float x = X[(size_t)r * C + c];
        s += x;
        q += x * x;
    }
    atomicAdd(&sum[c], s);
    atomicAdd(&sumsq[c], q);
}

__global__ void bn_finalize_kernel(const float* __restrict__ sum, const float* __restrict__ sumsq,
                                   const float* __restrict__ gamma, const float* __restrict__ beta,
                                   float* __restrict__ scale, float* __restrict__ shift,
                                   float inv_n) {
    int c = threadIdx.x;
    float m = sum[c] * inv_n;
    float var = sumsq[c] * inv_n - m * m;
    float rs = rsqrtf(var + 1e-5f);
    float sc = gamma[c] * rs;
    scale[c] = sc;
    shift[c] = beta[c] - sc * m;
}

__global__ void bn_apply_relu_kernel(const float* __restrict__ X, float* __restrict__ Y,
                                     const float* __restrict__ scale,
                                     const float* __restrict__ shift,
                                     int n4, int c4mask) {
    int i = blockIdx.x * blockDim.x + threadIdx.x;
    if (i >= n4) return;
    int c = (i & c4mask) << 2;
    float4 x = ((const float4*)X)[i];
    float4 sc = *(const float4*)(scale + c);
    float4 sh = *(const float4*)(shift + c);
    float4 y;
    y.x = fmaxf(0.f, x.x * sc.x + sh.x);
    y.y = fmaxf(0.f, x.y * sc.y + sh.y);
    y.z = fmaxf(0.f, x.z * sc.z + sh.z);
    y.w = fmaxf(0.f, x.w * sc.w + sh.w);
    ((float4*)Y)[i] = y;
}

extern "C" void kernel_launch(void* const* d_in, const int* in_sizes, int n_in,
                              void* d_out, int out_size, void* d_ws, size_t ws_size,
                              hipStream_t stream) {
    const float* v    = (const float*)d_in[0];
    const int* src    = (const int*)d_in[1];
    const int* dst    = (const int*)d_in[2];
    const float* ew   = (const float*)d_in[3];
    const float* eps  = (const float*)d_in[4];
    const float* W1   = (const float*)d_in[5];
    const float* b1   = (const float*)d_in[6];
    const float* g1   = (const float*)d_in[7];
    const float* be1  = (const float*)d_in[8];
    const float* W2   = (const float*)d_in[9];
    const float* b2   = (const float*)d_in[10];
    const float* g2   = (const float*)d_in[11];
    const float* be2  = (const float*)d_in[12];
    float* out = (float*)d_out;

    // workspace layout
    float* ws = (float*)d_ws;
    float* x1     = ws;                         // N*512 = 25,600,000 floats
    float* sum1   = ws + 25600000;              // 512
    float* sumsq1 = sum1 + 512;                 // 512
    float* sum2   = sumsq1 + 512;               // 128
    float* sumsq2 = sum2 + 128;                 // 128
    float* scale1 = sumsq2 + 128;               // 512
    float* shift1 = scale1 + 512;               // 512
    float* scale2 = shift1 + 512;               // 128
    float* shift2 = scale2 + 128;               // 128
    int*   counts    = (int*)(ws + 25602560);   // 50,000
    int*   cursor    = counts + 50000;          // 50,000
    int*   row_start = cursor + 50000;          // 50,001 (+pad)
    int*   csr_src   = row_start + 50004;       // 800,000
    float* csr_w     = (float*)(csr_src + 800000); // 800,000

    // vagg lives in d_out (same shape [N,128]); GEMM2 overwrites it later.
    float* vagg = out;

    // zero: stats (2560 f) + counts (50k) + cursor (50k)  — one contiguous region
    hipMemsetAsync(sum1, 0, (size_t)(2560 + 50000 + 50000) * sizeof(float), stream);

    // CSR build
    hist_kernel<<<(E_EDGES + 255) / 256, 256, 0, stream>>>(dst, counts);
    scan_kernel<<<1, 1024, 0, stream>>>(counts, row_start);
    fill_kernel<<<(E_EDGES + 255) / 256, 256, 0, stream>>>(src, dst, ew, row_start, cursor,
                                                           csr_src, csr_w);
    // gather + epsilon residual fused
    gather_kernel<<<(N_NODES + 7) / 8, 256, 0, stream>>>(v, row_start, csr_src, csr_w, eps, vagg);

    // GEMM1: x1 = vagg @ W1 + b1
    {
        dim3 grid(D_HIDF / 64, (N_NODES + 63) / 64);
        gemm_bias_kernel<<<grid, 256, 0, stream>>>(vagg, W1, b1, x1, N_NODES, D_HIDF, D_INF);
    }
    // BN1 + ReLU in-place
    {
        int rpb = 256;
        int blocks = (N_NODES + rpb - 1) / rpb;
        bn_stats_kernel<<<blocks, D_HIDF, 0, stream>>>(x1, sum1, sumsq1, N_NODES, D_HIDF, rpb);
        bn_finalize_kernel<<<1, D_HIDF, 0, stream>>>(sum1, sumsq1, g1, be1, scale1, shift1, 1.0f / N_NODES);
        int n4 = N_NODES * D_HIDF / 4;
        bn_apply_relu_kernel<<<(n4 + 255) / 256, 256, 0, stream>>>(x1, x1, scale1, shift1, n4, 127);
    }
    // GEMM2: out = h @ W2 + b2  (overwrites vagg scratch)
    {
        dim3 grid(D_OUTF / 64, (N_NODES + 63) / 64);
        gemm_bias_kernel<<<grid, 256, 0, stream>>>(x1, W2, b2, out, N_NODES, D_OUTF, D_HIDF);
    }
    // BN2 + ReLU in-place on d_out
    {
        int rpb = 256;
        int blocks = (N_NODES + rpb - 1) / rpb;
        bn_stats_kernel<<<blocks, D_OUTF, 0, stream>>>(out, sum2, sumsq2, N_NODES, D_OUTF, rpb);
        bn_finalize_kernel<<<1, D_OUTF, 0, stream>>>(sum2, sumsq2, g2, be2, scale2, shift2, 1.0f / N_NODES);
        int n4 = N_NODES * D_OUTF / 4;
        bn_apply_relu_kernel<<<(n4 + 255) / 256, 256, 0, stream>>>(out, out, scale2, shift2, n4, 31);
    }
}

// Round 3
// 471.684 us; speedup vs baseline: 3.9389x; 1.5433x over previous
//
#include <hip/hip_runtime.h>

#define N_NODES 50000
#define E_EDGES 800000
#define D_INF   128
#define D_HIDF  512
#define D_OUTF  128

typedef unsigned short u16;
typedef __attribute__((ext_vector_type(8))) short short8;
typedef __attribute__((ext_vector_type(4))) float floatx4;

__device__ __forceinline__ u16 f2bf(float f) {
    union { float f; unsigned u; } v; v.f = f;
    unsigned r = (v.u + 0x7fffu + ((v.u >> 16) & 1u)) >> 16;
    return (u16)r;
}
__device__ __forceinline__ float bf2f(u16 b) {
    union { unsigned u; float f; } v; v.u = ((unsigned)b) << 16; return v.f;
}

// ---------------- CSR build ----------------
__global__ void hist_kernel(const int* __restrict__ dst, int* __restrict__ counts) {
    int e = blockIdx.x * blockDim.x + threadIdx.x;
    if (e >= E_EDGES) return;
    atomicAdd(&counts[dst[e]], 1);
}

__global__ __launch_bounds__(1024) void scan_kernel(const int* __restrict__ counts,
                                                    int* __restrict__ row_start) {
    __shared__ int partial[1024];
    const int tid = threadIdx.x;
    const int CH = (N_NODES + 1023) / 1024;
    const int base = tid * CH;
    int s = 0;
    for (int i = 0; i < CH; ++i) {
        int idx = base + i;
        if (idx < N_NODES) s += counts[idx];
    }
    partial[tid] = s;
    __syncthreads();
    for (int off = 1; off < 1024; off <<= 1) {
        int v = (tid >= off) ? partial[tid - off] : 0;
        __syncthreads();
        partial[tid] += v;
        __syncthreads();
    }
    int prefix = (tid == 0) ? 0 : partial[tid - 1];
    for (int i = 0; i < CH; ++i) {
        int idx = base + i;
        if (idx < N_NODES) {
            row_start[idx] = prefix;
            prefix += counts[idx];
        }
    }
    if (tid == 1023) row_start[N_NODES] = prefix;
}

__global__ void fill_kernel(const int* __restrict__ src, const int* __restrict__ dst,
                            const float* __restrict__ w,
                            const int* __restrict__ row_start, int* __restrict__ cursor,
                            int* __restrict__ csr_src, float* __restrict__ csr_w) {
    int e = blockIdx.x * blockDim.x + threadIdx.x;
    if (e >= E_EDGES) return;
    int d = dst[e];
    int pos = atomicAdd(&cursor[d], 1);
    int idx = row_start[d] + pos;
    csr_src[idx] = src[e];
    csr_w[idx]   = w[e];
}

// ---------------- gather: vagg_bf16[n] = sum_j w_j * v[src_j] + eps * v[n] ----------------
__global__ __launch_bounds__(256) void gather_kernel(const float* __restrict__ v,
                                                     const int* __restrict__ row_start,
                                                     const int* __restrict__ csr_src,
                                                     const float* __restrict__ csr_w,
                                                     const float* __restrict__ eps_p,
                                                     u16* __restrict__ vagg) {
    int node = blockIdx.x * 8 + (threadIdx.x >> 5);
    if (node >= N_NODES) return;
    int lane4 = (threadIdx.x & 31) << 2;
    int beg = row_start[node];
    int end = row_start[node + 1];
    float ax = 0.f, ay = 0.f, az = 0.f, aw = 0.f;
    for (int j = beg; j < end; ++j) {
        int s = csr_src[j];
        float we = csr_w[j];
        const float4 vv = *(const float4*)(v + (size_t)s * D_INF + lane4);
        ax += we * vv.x; ay += we * vv.y; az += we * vv.z; aw += we * vv.w;
    }
    float e = eps_p[0];
    const float4 vn = *(const float4*)(v + (size_t)node * D_INF + lane4);
    ushort4 o;
    o.x = f2bf(ax + e * vn.x);
    o.y = f2bf(ay + e * vn.y);
    o.z = f2bf(az + e * vn.z);
    o.w = f2bf(aw + e * vn.w);
    *(ushort4*)(vagg + (size_t)node * D_INF + lane4) = o;
}

// ---------------- weight prep: cast + transpose to bf16 B^T layout ----------------
__global__ void prep_weights_kernel(const float* __restrict__ W1, const float* __restrict__ W2,
                                    u16* __restrict__ W1t, u16* __restrict__ W2t) {
    int idx = blockIdx.x * blockDim.x + threadIdx.x;
    if (idx >= 128 * 512) return;
    int k1 = idx >> 9, n1 = idx & 511;      // W1 [128][512]
    W1t[n1 * 128 + k1] = f2bf(W1[idx]);
    int k2 = idx >> 7, n2 = idx & 127;      // W2 [512][128]
    W2t[n2 * 512 + k2] = f2bf(W2[idx]);
}

// ---------------- MFMA GEMM + bias + fused BN stats ----------------
// C[M,N] = A[M,K](bf16) * Bt[N,K](bf16)^T + bias; per-column sum/sumsq via atomics.
// 128x128 tile, BK=32, 256 threads (4 waves, 2x2), 4x4 16x16x32 frags per wave.
template<int OUT_BF16>
__global__ __launch_bounds__(256) void mfma_gemm_bn(
        const u16* __restrict__ A, const u16* __restrict__ Bt,
        const float* __restrict__ bias, void* __restrict__ Cout,
        float* __restrict__ sum, float* __restrict__ sumsq,
        int M, int Ncols, int K) {
    __shared__ u16 As[128 * 40];   // +8 halves pad per row
    __shared__ u16 Bs[128 * 40];
    const int bm = blockIdx.y * 128;
    const int bn = blockIdx.x * 128;
    const int tid = threadIdx.x;
    const int wave = tid >> 6, lane = tid & 63;
    const int wm = (wave >> 1) * 64, wn = (wave & 1) * 64;
    const int lm = lane & 15, quad = lane >> 4;

    floatx4 acc[4][4] = {};

    const int ksteps = K >> 5;
    for (int ks = 0; ks < ksteps; ++ks) {
        const int k0 = ks << 5;
#pragma unroll
        for (int c = 0; c < 2; ++c) {
            int chunk = tid + (c << 8);        // 0..511
            int r = chunk >> 2;                // 0..127
            int kk = (chunk & 3) << 3;         // 0,8,16,24
            int row = bm + r;
            float4 av = make_float4(0.f, 0.f, 0.f, 0.f);
            if (row < M) av = *(const float4*)(A + (size_t)row * K + k0 + kk);
            *(float4*)&As[r * 40 + kk] = av;
            float4 bv = *(const float4*)(Bt + (size_t)(bn + r) * K + k0 + kk);
            *(float4*)&Bs[r * 40 + kk] = bv;
        }
        __syncthreads();
        short8 af[4], bfr[4];
#pragma unroll
        for (int i = 0; i < 4; ++i)
            af[i] = *(const short8*)&As[(wm + i * 16 + lm) * 40 + quad * 8];
#pragma unroll
        for (int j = 0; j < 4; ++j)
            bfr[j] = *(const short8*)&Bs[(wn + j * 16 + lm) * 40 + quad * 8];
#pragma unroll
        for (int i = 0; i < 4; ++i)
#pragma unroll
            for (int j = 0; j < 4; ++j)
                acc[i][j] = __builtin_amdgcn_mfma_f32_16x16x32_bf16(af[i], bfr[j], acc[i][j], 0, 0, 0);
        __syncthreads();
    }

    // epilogue: bias, store, fused per-column stats (exact fp32 accumulators)
#pragma unroll
    for (int j = 0; j < 4; ++j) {
        int col = bn + wn + j * 16 + lm;
        float bj = bias[col];
        float s = 0.f, q = 0.f;
#pragma unroll
        for (int i = 0; i < 4; ++i) {
            int row0 = bm + wm + i * 16 + quad * 4;
#pragma unroll
            for (int r = 0; r < 4; ++r) {
                int row = row0 + r;
                float x = acc[i][j][r] + bj;
                if (row < M) {
                    s += x; q += x * x;
                    if (OUT_BF16) ((u16*)Cout)[(size_t)row * Ncols + col] = f2bf(x);
                    else          ((float*)Cout)[(size_t)row * Ncols + col] = x;
                }
            }
        }
        s += __shfl_xor(s, 16); q += __shfl_xor(q, 16);
        s += __shfl_xor(s, 32); q += __shfl_xor(q, 32);
        if (quad == 0) {
            atomicAdd(&sum[col], s);
            atomicAdd(&sumsq[col], q);
        }
    }
}

// ---------------- BN finalize ----------------
__global__ void bn_finalize_kernel(const float* __restrict__ sum, const float* __restrict__ sumsq,
                                   const float* __restrict__ gamma, const float* __restrict__ beta,
                                   float* __restrict__ scale, float* __restrict__ shift,
                                   float inv_n) {
    int c = threadIdx.x;
    float m = sum[c] * inv_n;
    float var = sumsq[c] * inv_n - m * m;
    float rs = rsqrtf(var + 1e-5f);
    float sc = gamma[c] * rs;
    scale[c] = sc;
    shift[c] = beta[c] - sc * m;
}

// ---------------- BN apply + ReLU + cast (bf16 -> bf16), 8 elems/thread ----------------
__global__ void bn_apply_cast_kernel(const u16* __restrict__ X, u16* __restrict__ Y,
                                     const float* __restrict__ scale,
                                     const float* __restrict__ shift,
                                     int n8, int cmask) {
    int i = blockIdx.x * blockDim.x + threadIdx.x;
    if (i >= n8) return;
    int c = (i & cmask) << 3;
    float4 raw = ((const float4*)X)[i];
    const u16* xb = (const u16*)&raw;
    float4 sc0 = *(const float4*)(scale + c);
    float4 sc1 = *(const float4*)(scale + c + 4);
    float4 sh0 = *(const float4*)(shift + c);
    float4 sh1 = *(const float4*)(shift + c + 4);
    u16 ob[8];
    ob[0] = f2bf(fmaxf(0.f, bf2f(xb[0]) * sc0.x + sh0.x));
    ob[1] = f2bf(fmaxf(0.f, bf2f(xb[1]) * sc0.y + sh0.y));
    ob[2] = f2bf(fmaxf(0.f, bf2f(xb[2]) * sc0.z + sh0.z));
    ob[3] = f2bf(fmaxf(0.f, bf2f(xb[3]) * sc0.w + sh0.w));
    ob[4] = f2bf(fmaxf(0.f, bf2f(xb[4]) * sc1.x + sh1.x));
    ob[5] = f2bf(fmaxf(0.f, bf2f(xb[5]) * sc1.y + sh1.y));
    ob[6] = f2bf(fmaxf(0.f, bf2f(xb[6]) * sc1.z + sh1.z));
    ob[7] = f2bf(fmaxf(0.f, bf2f(xb[7]) * sc1.w + sh1.w));
    ((float4*)Y)[i] = *(const float4*)ob;
}

// ---------------- BN apply + ReLU fp32 in-place (final output) ----------------
__global__ void bn_apply_relu_kernel(float* __restrict__ X,
                                     const float* __restrict__ scale,
                                     const float* __restrict__ shift,
                                     int n4, int c4mask) {
    int i = blockIdx.x * blockDim.x + threadIdx.x;
    if (i >= n4) return;
    int c = (i & c4mask) << 2;
    float4 x = ((const float4*)X)[i];
    float4 sc = *(const float4*)(scale + c);
    float4 sh = *(const float4*)(shift + c);
    float4 y;
    y.x = fmaxf(0.f, x.x * sc.x + sh.x);
    y.y = fmaxf(0.f, x.y * sc.y + sh.y);
    y.z = fmaxf(0.f, x.z * sc.z + sh.z);
    y.w = fmaxf(0.f, x.w * sc.w + sh.w);
    ((float4*)X)[i] = y;
}

extern "C" void kernel_launch(void* const* d_in, const int* in_sizes, int n_in,
                              void* d_out, int out_size, void* d_ws, size_t ws_size,
                              hipStream_t stream) {
    const float* v    = (const float*)d_in[0];
    const int* src    = (const int*)d_in[1];
    const int* dst    = (const int*)d_in[2];
    const float* ew   = (const float*)d_in[3];
    const float* eps  = (const float*)d_in[4];
    const float* W1   = (const float*)d_in[5];
    const float* b1   = (const float*)d_in[6];
    const float* g1   = (const float*)d_in[7];
    const float* be1  = (const float*)d_in[8];
    const float* W2   = (const float*)d_in[9];
    const float* b2   = (const float*)d_in[10];
    const float* g2   = (const float*)d_in[11];
    const float* be2  = (const float*)d_in[12];
    float* out = (float*)d_out;

    // ---- workspace layout (bytes) ----
    char* base = (char*)d_ws;
    u16* x1  = (u16*)(base);                      // [N,512] bf16 = 51.2e6 B
    u16* hv  = (u16*)(base + 51200000ull);        // h [N,512] bf16; vagg bf16 shares this slot
    u16* W1t = (u16*)(base + 102400000ull);       // [512][128] bf16
    u16* W2t = (u16*)(base + 102531072ull);       // [128][512] bf16
    float* sum1   = (float*)(base + 102662144ull);
    float* sumsq1 = sum1 + 512;
    float* sum2   = sumsq1 + 512;
    float* sumsq2 = sum2 + 128;
    float* scale1 = sumsq2 + 128;
    float* shift1 = scale1 + 512;
    float* scale2 = shift1 + 512;
    float* shift2 = scale2 + 128;
    int* counts    = (int*)(shift2 + 128);
    int* cursor    = counts + 50000;
    int* row_start = cursor + 50000;              // 50001 (+pad 3)
    int* csr_src   = row_start + 50004;
    float* csr_w   = (float*)(csr_src + 800000);

    u16* vagg = hv;   // [N,128] bf16, dead after GEMM1; h overwrites it

    // zero: stats (1280f) + scale/shift (1280f, overwritten anyway) + counts + cursor
    hipMemsetAsync(sum1, 0, (size_t)(1280 + 1280 + 100000) * sizeof(float), stream);

    // CSR build + gather
    hist_kernel<<<(E_EDGES + 255) / 256, 256, 0, stream>>>(dst, counts);
    scan_kernel<<<1, 1024, 0, stream>>>(counts, row_start);
    fill_kernel<<<(E_EDGES + 255) / 256, 256, 0, stream>>>(src, dst, ew, row_start, cursor,
                                                           csr_src, csr_w);
    prep_weights_kernel<<<(128 * 512 + 255) / 256, 256, 0, stream>>>(W1, W2, W1t, W2t);
    gather_kernel<<<(N_NODES + 7) / 8, 256, 0, stream>>>(v, row_start, csr_src, csr_w, eps, vagg);

    // GEMM1 + BN1 stats: x1 = vagg @ W1 + b1 (bf16 out)
    {
        dim3 grid(D_HIDF / 128, (N_NODES + 127) / 128);
        mfma_gemm_bn<1><<<grid, 256, 0, stream>>>(vagg, W1t, b1, x1, sum1, sumsq1,
                                                  N_NODES, D_HIDF, D_INF);
    }
    bn_finalize_kernel<<<1, D_HIDF, 0, stream>>>(sum1, sumsq1, g1, be1, scale1, shift1,
                                                 1.0f / N_NODES);
    // BN1 apply + ReLU + cast -> h (overwrites vagg slot; vagg is dead)
    {
        int n8 = N_NODES * D_HIDF / 8;
        bn_apply_cast_kernel<<<(n8 + 255) / 256, 256, 0, stream>>>(x1, hv, scale1, shift1, n8, 63);
    }
    // GEMM2 + BN2 stats: out_raw = h @ W2 + b2 (fp32 out to d_out)
    {
        dim3 grid(D_OUTF / 128, (N_NODES + 127) / 128);
        mfma_gemm_bn<0><<<grid, 256, 0, stream>>>(hv, W2t, b2, out, sum2, sumsq2,
                                                  N_NODES, D_OUTF, D_HIDF);
    }
    bn_finalize_kernel<<<1, D_OUTF, 0, stream>>>(sum2, sumsq2, g2, be2, scale2, shift2,
                                                 1.0f / N_NODES);
    // BN2 apply + ReLU in-place on d_out
    {
        int n4 = N_NODES * D_OUTF / 4;
        bn_apply_relu_kernel<<<(n4 + 255) / 256, 256, 0, stream>>>(out, scale2, shift2, n4, 31);
    }
}

// Round 4
// 386.723 us; speedup vs baseline: 4.8043x; 1.2197x over previous
//
#include <hip/hip_runtime.h>

#define N_NODES 50000
#define E_EDGES 800000
#define D_INF   128
#define D_HIDF  512
#define D_OUTF  128
#define SCAN_NB ((N_NODES + 255) / 256)   // 196 blocks

typedef unsigned short u16;
typedef __attribute__((ext_vector_type(8))) short short8;
typedef __attribute__((ext_vector_type(4))) float floatx4;

__device__ __forceinline__ u16 f2bf(float f) {
    union { float f; unsigned u; } v; v.f = f;
    unsigned r = (v.u + 0x7fffu + ((v.u >> 16) & 1u)) >> 16;
    return (u16)r;
}
__device__ __forceinline__ float bf2f(u16 b) {
    union { unsigned u; float f; } v; v.u = ((unsigned)b) << 16; return v.f;
}

// ---------------- CSR build step 1: histogram of dst ----------------
__global__ void hist_kernel(const int* __restrict__ dst, int* __restrict__ counts) {
    int e = blockIdx.x * blockDim.x + threadIdx.x;
    if (e >= E_EDGES) return;
    atomicAdd(&counts[dst[e]], 1);
}

// ---------------- CSR build step 2: 3-phase parallel exclusive scan ----------------
__global__ __launch_bounds__(256) void reduce_kernel(const int* __restrict__ counts,
                                                     int* __restrict__ block_sums) {
    __shared__ int lsum[4];
    int tid = threadIdx.x;
    int gid = blockIdx.x * 256 + tid;
    int s = (gid < N_NODES) ? counts[gid] : 0;
#pragma unroll
    for (int off = 32; off; off >>= 1) s += __shfl_down(s, off);
    if ((tid & 63) == 0) lsum[tid >> 6] = s;
    __syncthreads();
    if (tid == 0) block_sums[blockIdx.x] = lsum[0] + lsum[1] + lsum[2] + lsum[3];
}

__global__ __launch_bounds__(256) void scan_block_sums(const int* __restrict__ block_sums,
                                                       int* __restrict__ block_offs) {
    __shared__ int sh[256];
    int tid = threadIdx.x;
    sh[tid] = (tid < SCAN_NB) ? block_sums[tid] : 0;
    __syncthreads();
    for (int off = 1; off < 256; off <<= 1) {
        int t = (tid >= off) ? sh[tid - off] : 0;
        __syncthreads();
        sh[tid] += t;
        __syncthreads();
    }
    if (tid < SCAN_NB) block_offs[tid] = (tid == 0) ? 0 : sh[tid - 1];
}

__global__ __launch_bounds__(256) void scan_final(const int* __restrict__ counts,
                                                  const int* __restrict__ block_offs,
                                                  int* __restrict__ row_start) {
    __shared__ int sh[256];
    int tid = threadIdx.x;
    int gid = blockIdx.x * 256 + tid;
    int v = (gid < N_NODES) ? counts[gid] : 0;
    sh[tid] = v;
    __syncthreads();
    for (int off = 1; off < 256; off <<= 1) {
        int t = (tid >= off) ? sh[tid - off] : 0;
        __syncthreads();
        sh[tid] += t;
        __syncthreads();
    }
    int excl = (tid == 0) ? 0 : sh[tid - 1];
    if (gid < N_NODES) row_start[gid] = block_offs[blockIdx.x] + excl;
    if (gid == 0) row_start[N_NODES] = E_EDGES;
}

// ---------------- CSR build step 3: fill ----------------
__global__ void fill_kernel(const int* __restrict__ src, const int* __restrict__ dst,
                            const float* __restrict__ w,
                            const int* __restrict__ row_start, int* __restrict__ cursor,
                            int* __restrict__ csr_src, float* __restrict__ csr_w) {
    int e = blockIdx.x * blockDim.x + threadIdx.x;
    if (e >= E_EDGES) return;
    int d = dst[e];
    int pos = atomicAdd(&cursor[d], 1);
    int idx = row_start[d] + pos;
    csr_src[idx] = src[e];
    csr_w[idx]   = w[e];
}

// ---------------- gather: vagg_bf16[n] = sum_j w_j * v[src_j] + eps * v[n] ----------------
__global__ __launch_bounds__(256) void gather_kernel(const float* __restrict__ v,
                                                     const int* __restrict__ row_start,
                                                     const int* __restrict__ csr_src,
                                                     const float* __restrict__ csr_w,
                                                     const float* __restrict__ eps_p,
                                                     u16* __restrict__ vagg) {
    int node = blockIdx.x * 8 + (threadIdx.x >> 5);
    if (node >= N_NODES) return;
    int lane4 = (threadIdx.x & 31) << 2;
    int beg = row_start[node];
    int end = row_start[node + 1];
    float ax = 0.f, ay = 0.f, az = 0.f, aw = 0.f;
    for (int j = beg; j < end; ++j) {
        int s = csr_src[j];
        float we = csr_w[j];
        const float4 vv = *(const float4*)(v + (size_t)s * D_INF + lane4);
        ax += we * vv.x; ay += we * vv.y; az += we * vv.z; aw += we * vv.w;
    }
    float e = eps_p[0];
    const float4 vn = *(const float4*)(v + (size_t)node * D_INF + lane4);
    ushort4 o;
    o.x = f2bf(ax + e * vn.x);
    o.y = f2bf(ay + e * vn.y);
    o.z = f2bf(az + e * vn.z);
    o.w = f2bf(aw + e * vn.w);
    *(ushort4*)(vagg + (size_t)node * D_INF + lane4) = o;
}

// ---------------- weight prep: cast + transpose to bf16 B^T layout ----------------
__global__ void prep_weights_kernel(const float* __restrict__ W1, const float* __restrict__ W2,
                                    u16* __restrict__ W1t, u16* __restrict__ W2t) {
    int idx = blockIdx.x * blockDim.x + threadIdx.x;
    if (idx >= 128 * 512) return;
    int k1 = idx >> 9, n1 = idx & 511;      // W1 [128][512]
    W1t[n1 * 128 + k1] = f2bf(W1[idx]);
    int k2 = idx >> 7, n2 = idx & 127;      // W2 [512][128]
    W2t[n2 * 512 + k2] = f2bf(W2[idx]);
}

// ---------------- MFMA GEMM + bias + fused BN stats ----------------
template<int OUT_BF16>
__global__ __launch_bounds__(256) void mfma_gemm_bn(
        const u16* __restrict__ A, const u16* __restrict__ Bt,
        const float* __restrict__ bias, void* __restrict__ Cout,
        float* __restrict__ sum, float* __restrict__ sumsq,
        int M, int Ncols, int K) {
    __shared__ u16 As[128 * 40];
    __shared__ u16 Bs[128 * 40];
    const int bm = blockIdx.y * 128;
    const int bn = blockIdx.x * 128;
    const int tid = threadIdx.x;
    const int wave = tid >> 6, lane = tid & 63;
    const int wm = (wave >> 1) * 64, wn = (wave & 1) * 64;
    const int lm = lane & 15, quad = lane >> 4;

    floatx4 acc[4][4] = {};

    const int ksteps = K >> 5;
    for (int ks = 0; ks < ksteps; ++ks) {
        const int k0 = ks << 5;
#pragma unroll
        for (int c = 0; c < 2; ++c) {
            int chunk = tid + (c << 8);
            int r = chunk >> 2;
            int kk = (chunk & 3) << 3;
            int row = bm + r;
            float4 av = make_float4(0.f, 0.f, 0.f, 0.f);
            if (row < M) av = *(const float4*)(A + (size_t)row * K + k0 + kk);
            *(float4*)&As[r * 40 + kk] = av;
            float4 bv = *(const float4*)(Bt + (size_t)(bn + r) * K + k0 + kk);
            *(float4*)&Bs[r * 40 + kk] = bv;
        }
        __syncthreads();
        short8 af[4], bfr[4];
#pragma unroll
        for (int i = 0; i < 4; ++i)
            af[i] = *(const short8*)&As[(wm + i * 16 + lm) * 40 + quad * 8];
#pragma unroll
        for (int j = 0; j < 4; ++j)
            bfr[j] = *(const short8*)&Bs[(wn + j * 16 + lm) * 40 + quad * 8];
#pragma unroll
        for (int i = 0; i < 4; ++i)
#pragma unroll
            for (int j = 0; j < 4; ++j)
                acc[i][j] = __builtin_amdgcn_mfma_f32_16x16x32_bf16(af[i], bfr[j], acc[i][j], 0, 0, 0);
        __syncthreads();
    }

#pragma unroll
    for (int j = 0; j < 4; ++j) {
        int col = bn + wn + j * 16 + lm;
        float bj = bias[col];
        float s = 0.f, q = 0.f;
#pragma unroll
        for (int i = 0; i < 4; ++i) {
            int row0 = bm + wm + i * 16 + quad * 4;
#pragma unroll
            for (int r = 0; r < 4; ++r) {
                int row = row0 + r;
                float x = acc[i][j][r] + bj;
                if (row < M) {
                    s += x; q += x * x;
                    if (OUT_BF16) ((u16*)Cout)[(size_t)row * Ncols + col] = f2bf(x);
                    else          ((float*)Cout)[(size_t)row * Ncols + col] = x;
                }
            }
        }
        s += __shfl_xor(s, 16); q += __shfl_xor(q, 16);
        s += __shfl_xor(s, 32); q += __shfl_xor(q, 32);
        if (quad == 0) {
            atomicAdd(&sum[col], s);
            atomicAdd(&sumsq[col], q);
        }
    }
}

// ---------------- BN finalize ----------------
__global__ void bn_finalize_kernel(const float* __restrict__ sum, const float* __restrict__ sumsq,
                                   const float* __restrict__ gamma, const float* __restrict__ beta,
                                   float* __restrict__ scale, float* __restrict__ shift,
                                   float inv_n) {
    int c = threadIdx.x;
    float m = sum[c] * inv_n;
    float var = sumsq[c] * inv_n - m * m;
    float rs = rsqrtf(var + 1e-5f);
    float sc = gamma[c] * rs;
    scale[c] = sc;
    shift[c] = beta[c] - sc * m;
}

// ---------------- BN apply + ReLU + cast (bf16 -> bf16) ----------------
__global__ void bn_apply_cast_kernel(const u16* __restrict__ X, u16* __restrict__ Y,
                                     const float* __restrict__ scale,
                                     const float* __restrict__ shift,
                                     int n8, int cmask) {
    int i = blockIdx.x * blockDim.x + threadIdx.x;
    if (i >= n8) return;
    int c = (i & cmask) << 3;
    float4 raw = ((const float4*)X)[i];
    const u16* xb = (const u16*)&raw;
    float4 sc0 = *(const float4*)(scale + c);
    float4 sc1 = *(const float4*)(scale + c + 4);
    float4 sh0 = *(const float4*)(shift + c);
    float4 sh1 = *(const float4*)(shift + c + 4);
    u16 ob[8];
    ob[0] = f2bf(fmaxf(0.f, bf2f(xb[0]) * sc0.x + sh0.x));
    ob[1] = f2bf(fmaxf(0.f, bf2f(xb[1]) * sc0.y + sh0.y));
    ob[2] = f2bf(fmaxf(0.f, bf2f(xb[2]) * sc0.z + sh0.z));
    ob[3] = f2bf(fmaxf(0.f, bf2f(xb[3]) * sc0.w + sh0.w));
    ob[4] = f2bf(fmaxf(0.f, bf2f(xb[4]) * sc1.x + sh1.x));
    ob[5] = f2bf(fmaxf(0.f, bf2f(xb[5]) * sc1.y + sh1.y));
    ob[6] = f2bf(fmaxf(0.f, bf2f(xb[6]) * sc1.z + sh1.z));
    ob[7] = f2bf(fmaxf(0.f, bf2f(xb[7]) * sc1.w + sh1.w));
    ((float4*)Y)[i] = *(const float4*)ob;
}

// ---------------- BN apply + ReLU fp32 in-place ----------------
__global__ void bn_apply_relu_kernel(float* __restrict__ X,
                                     const float* __restrict__ scale,
                                     const float* __restrict__ shift,
                                     int n4, int c4mask) {
    int i = blockIdx.x * blockDim.x + threadIdx.x;
    if (i >= n4) return;
    int c = (i & c4mask) << 2;
    float4 x = ((const float4*)X)[i];
    float4 sc = *(const float4*)(scale + c);
    float4 sh = *(const float4*)(shift + c);
    float4 y;
    y.x = fmaxf(0.f, x.x * sc.x + sh.x);
    y.y = fmaxf(0.f, x.y * sc.y + sh.y);
    y.z = fmaxf(0.f, x.z * sc.z + sh.z);
    y.w = fmaxf(0.f, x.w * sc.w + sh.w);
    ((float4*)X)[i] = y;
}

extern "C" void kernel_launch(void* const* d_in, const int* in_sizes, int n_in,
                              void* d_out, int out_size, void* d_ws, size_t ws_size,
                              hipStream_t stream) {
    const float* v    = (const float*)d_in[0];
    const int* src    = (const int*)d_in[1];
    const int* dst    = (const int*)d_in[2];
    const float* ew   = (const float*)d_in[3];
    const float* eps  = (const float*)d_in[4];
    const float* W1   = (const float*)d_in[5];
    const float* b1   = (const float*)d_in[6];
    const float* g1   = (const float*)d_in[7];
    const float* be1  = (const float*)d_in[8];
    const float* W2   = (const float*)d_in[9];
    const float* b2   = (const float*)d_in[10];
    const float* g2   = (const float*)d_in[11];
    const float* be2  = (const float*)d_in[12];
    float* out = (float*)d_out;

    // ---- workspace layout (bytes) ----
    char* base = (char*)d_ws;
    u16* x1  = (u16*)(base);                      // [N,512] bf16
    u16* hv  = (u16*)(base + 51200000ull);        // h / vagg slot
    u16* W1t = (u16*)(base + 102400000ull);
    u16* W2t = (u16*)(base + 102531072ull);
    float* sum1   = (float*)(base + 102662144ull);
    float* sumsq1 = sum1 + 512;
    float* sum2   = sumsq1 + 512;
    float* sumsq2 = sum2 + 128;
    float* scale1 = sumsq2 + 128;
    float* shift1 = scale1 + 512;
    float* scale2 = shift1 + 512;
    float* shift2 = scale2 + 128;
    int* counts     = (int*)(shift2 + 128);
    int* cursor     = counts + 50000;
    int* row_start  = cursor + 50000;             // 50001 (+pad 3)
    int* csr_src    = row_start + 50004;
    float* csr_w    = (float*)(csr_src + 800000);
    int* block_sums = (int*)(csr_w + 800000);     // 256
    int* block_offs = block_sums + 256;           // 256

    u16* vagg = hv;

    // zero: stats + scale/shift + counts + cursor
    hipMemsetAsync(sum1, 0, (size_t)(1280 + 1280 + 100000) * sizeof(float), stream);

    // CSR build
    hist_kernel<<<(E_EDGES + 255) / 256, 256, 0, stream>>>(dst, counts);
    reduce_kernel<<<SCAN_NB, 256, 0, stream>>>(counts, block_sums);
    scan_block_sums<<<1, 256, 0, stream>>>(block_sums, block_offs);
    scan_final<<<SCAN_NB, 256, 0, stream>>>(counts, block_offs, row_start);
    fill_kernel<<<(E_EDGES + 255) / 256, 256, 0, stream>>>(src, dst, ew, row_start, cursor,
                                                           csr_src, csr_w);
    prep_weights_kernel<<<(128 * 512 + 255) / 256, 256, 0, stream>>>(W1, W2, W1t, W2t);
    gather_kernel<<<(N_NODES + 7) / 8, 256, 0, stream>>>(v, row_start, csr_src, csr_w, eps, vagg);

    // GEMM1 + BN1 stats
    {
        dim3 grid(D_HIDF / 128, (N_NODES + 127) / 128);
        mfma_gemm_bn<1><<<grid, 256, 0, stream>>>(vagg, W1t, b1, x1, sum1, sumsq1,
                                                  N_NODES, D_HIDF, D_INF);
    }
    bn_finalize_kernel<<<1, D_HIDF, 0, stream>>>(sum1, sumsq1, g1, be1, scale1, shift1,
                                                 1.0f / N_NODES);
    {
        int n8 = N_NODES * D_HIDF / 8;
        bn_apply_cast_kernel<<<(n8 + 255) / 256, 256, 0, stream>>>(x1, hv, scale1, shift1, n8, 63);
    }
    // GEMM2 + BN2 stats
    {
        dim3 grid(D_OUTF / 128, (N_NODES + 127) / 128);
        mfma_gemm_bn<0><<<grid, 256, 0, stream>>>(hv, W2t, b2, out, sum2, sumsq2,
                                                  N_NODES, D_OUTF, D_HIDF);
    }
    bn_finalize_kernel<<<1, D_OUTF, 0, stream>>>(sum2, sumsq2, g2, be2, scale2, shift2,
                                                 1.0f / N_NODES);
    {
        int n4 = N_NODES * D_OUTF / 4;
        bn_apply_relu_kernel<<<(n4 + 255) / 256, 256, 0, stream>>>(out, scale2, shift2, n4, 31);
    }
}

// Round 5
// 372.396 us; speedup vs baseline: 4.9891x; 1.0385x over previous
//
#include <hip/hip_runtime.h>

#define N_NODES 50000
#define E_EDGES 800000
#define D_INF   128
#define D_HIDF  512
#define D_OUTF  128
#define SCAN_NB ((N_NODES + 255) / 256)   // 196 blocks

typedef unsigned short u16;
typedef __attribute__((ext_vector_type(8))) short short8;
typedef __attribute__((ext_vector_type(4))) float floatx4;

__device__ __forceinline__ u16 f2bf(float f) {
    union { float f; unsigned u; } v; v.f = f;
    unsigned r = (v.u + 0x7fffu + ((v.u >> 16) & 1u)) >> 16;
    return (u16)r;
}
__device__ __forceinline__ float bf2f(u16 b) {
    union { unsigned u; float f; } v; v.u = ((unsigned)b) << 16; return v.f;
}

// ---------------- CSR build step 1: histogram of dst ----------------
__global__ void hist_kernel(const int* __restrict__ dst, int* __restrict__ counts) {
    int e = blockIdx.x * blockDim.x + threadIdx.x;
    if (e >= E_EDGES) return;
    atomicAdd(&counts[dst[e]], 1);
}

// ---------------- CSR build step 2: 3-phase parallel exclusive scan ----------------
__global__ __launch_bounds__(256) void reduce_kernel(const int* __restrict__ counts,
                                                     int* __restrict__ block_sums) {
    __shared__ int lsum[4];
    int tid = threadIdx.x;
    int gid = blockIdx.x * 256 + tid;
    int s = (gid < N_NODES) ? counts[gid] : 0;
#pragma unroll
    for (int off = 32; off; off >>= 1) s += __shfl_down(s, off);
    if ((tid & 63) == 0) lsum[tid >> 6] = s;
    __syncthreads();
    if (tid == 0) block_sums[blockIdx.x] = lsum[0] + lsum[1] + lsum[2] + lsum[3];
}

__global__ __launch_bounds__(256) void scan_block_sums(const int* __restrict__ block_sums,
                                                       int* __restrict__ block_offs) {
    __shared__ int sh[256];
    int tid = threadIdx.x;
    sh[tid] = (tid < SCAN_NB) ? block_sums[tid] : 0;
    __syncthreads();
    for (int off = 1; off < 256; off <<= 1) {
        int t = (tid >= off) ? sh[tid - off] : 0;
        __syncthreads();
        sh[tid] += t;
        __syncthreads();
    }
    if (tid < SCAN_NB) block_offs[tid] = (tid == 0) ? 0 : sh[tid - 1];
}

__global__ __launch_bounds__(256) void scan_final(const int* __restrict__ counts,
                                                  const int* __restrict__ block_offs,
                                                  int* __restrict__ row_start) {
    __shared__ int sh[256];
    int tid = threadIdx.x;
    int gid = blockIdx.x * 256 + tid;
    int v = (gid < N_NODES) ? counts[gid] : 0;
    sh[tid] = v;
    __syncthreads();
    for (int off = 1; off < 256; off <<= 1) {
        int t = (tid >= off) ? sh[tid - off] : 0;
        __syncthreads();
        sh[tid] += t;
        __syncthreads();
    }
    int excl = (tid == 0) ? 0 : sh[tid - 1];
    if (gid < N_NODES) row_start[gid] = block_offs[blockIdx.x] + excl;
    if (gid == 0) row_start[N_NODES] = E_EDGES;
}

// ---------------- CSR build step 3: fill (interleaved {src, w} int2) ----------------
__global__ void fill_kernel(const int* __restrict__ src, const int* __restrict__ dst,
                            const float* __restrict__ w,
                            const int* __restrict__ row_start, int* __restrict__ cursor,
                            int2* __restrict__ csr_ew) {
    int e = blockIdx.x * blockDim.x + threadIdx.x;
    if (e >= E_EDGES) return;
    int d = dst[e];
    int pos = atomicAdd(&cursor[d], 1);
    int idx = row_start[d] + pos;
    int2 rec;
    rec.x = src[e];
    rec.y = __float_as_int(w[e]);
    csr_ew[idx] = rec;
}

// ---------------- cast v -> bf16 ----------------
__global__ void cast_v_kernel(const float* __restrict__ v, u16* __restrict__ vbf) {
    int i = blockIdx.x * blockDim.x + threadIdx.x;
    if (i >= N_NODES * D_INF / 8) return;
    const float4 a = ((const float4*)v)[i * 2];
    const float4 b = ((const float4*)v)[i * 2 + 1];
    u16 o[8];
    o[0] = f2bf(a.x); o[1] = f2bf(a.y); o[2] = f2bf(a.z); o[3] = f2bf(a.w);
    o[4] = f2bf(b.x); o[5] = f2bf(b.y); o[6] = f2bf(b.z); o[7] = f2bf(b.w);
    ((float4*)vbf)[i] = *(const float4*)o;
}

// ---------------- gather (bf16 rows): vagg[n] = sum_j w_j * vbf[src_j] + eps * vbf[n] ----------------
// 32 lanes per node, ushort4 (4 bf16 = 8B) per lane; 256B contiguous per edge row.
__global__ __launch_bounds__(256) void gather_kernel(const u16* __restrict__ vbf,
                                                     const int* __restrict__ row_start,
                                                     const int2* __restrict__ csr_ew,
                                                     const float* __restrict__ eps_p,
                                                     u16* __restrict__ vagg) {
    int node = blockIdx.x * 8 + (threadIdx.x >> 5);
    if (node >= N_NODES) return;
    int lane4 = (threadIdx.x & 31) << 2;
    int beg = row_start[node];
    int end = row_start[node + 1];
    float ax = 0.f, ay = 0.f, az = 0.f, aw = 0.f;
    for (int j = beg; j < end; ++j) {
        int2 ew = csr_ew[j];                       // broadcast 8B load
        float we = __int_as_float(ew.y);
        const ushort4 vv = *(const ushort4*)(vbf + (size_t)ew.x * D_INF + lane4);
        ax += we * bf2f(vv.x);
        ay += we * bf2f(vv.y);
        az += we * bf2f(vv.z);
        aw += we * bf2f(vv.w);
    }
    float e = eps_p[0];
    const ushort4 vn = *(const ushort4*)(vbf + (size_t)node * D_INF + lane4);
    ushort4 o;
    o.x = f2bf(ax + e * bf2f(vn.x));
    o.y = f2bf(ay + e * bf2f(vn.y));
    o.z = f2bf(az + e * bf2f(vn.z));
    o.w = f2bf(aw + e * bf2f(vn.w));
    *(ushort4*)(vagg + (size_t)node * D_INF + lane4) = o;
}

// ---------------- weight prep: cast + transpose to bf16 B^T layout ----------------
__global__ void prep_weights_kernel(const float* __restrict__ W1, const float* __restrict__ W2,
                                    u16* __restrict__ W1t, u16* __restrict__ W2t) {
    int idx = blockIdx.x * blockDim.x + threadIdx.x;
    if (idx >= 128 * 512) return;
    int k1 = idx >> 9, n1 = idx & 511;      // W1 [128][512]
    W1t[n1 * 128 + k1] = f2bf(W1[idx]);
    int k2 = idx >> 7, n2 = idx & 127;      // W2 [512][128]
    W2t[n2 * 512 + k2] = f2bf(W2[idx]);
}

// ---------------- MFMA GEMM + bias + fused BN stats (+optional fused BN-apply on A) ----------------
// C[M,N] = relu_bn_opt(A)[M,K](bf16) * Bt[N,K]^T + bias; per-column sum/sumsq via atomics.
// 128x128 tile, BK=32, 256 threads (4 waves, 2x2), 4x4 16x16x32 frags per wave.
template<int OUT_BF16, int FUSE_A_BN>
__global__ __launch_bounds__(256) void mfma_gemm_bn(
        const u16* __restrict__ A, const u16* __restrict__ Bt,
        const float* __restrict__ bias,
        const float* __restrict__ a_scale, const float* __restrict__ a_shift,
        void* __restrict__ Cout,
        float* __restrict__ sum, float* __restrict__ sumsq,
        int M, int Ncols, int K) {
    __shared__ u16 As[128 * 40];
    __shared__ u16 Bs[128 * 40];
    const int bm = blockIdx.y * 128;
    const int bn = blockIdx.x * 128;
    const int tid = threadIdx.x;
    const int wave = tid >> 6, lane = tid & 63;
    const int wm = (wave >> 1) * 64, wn = (wave & 1) * 64;
    const int lm = lane & 15, quad = lane >> 4;

    floatx4 acc[4][4] = {};

    const int ksteps = K >> 5;
    for (int ks = 0; ks < ksteps; ++ks) {
        const int k0 = ks << 5;
#pragma unroll
        for (int c = 0; c < 2; ++c) {
            int chunk = tid + (c << 8);
            int r = chunk >> 2;
            int kk = (chunk & 3) << 3;
            int row = bm + r;
            float4 av = make_float4(0.f, 0.f, 0.f, 0.f);
            if (row < M) {
                av = *(const float4*)(A + (size_t)row * K + k0 + kk);
                if (FUSE_A_BN) {
                    u16* ab = (u16*)&av;
                    const float4 s0 = *(const float4*)(a_scale + k0 + kk);
                    const float4 s1 = *(const float4*)(a_scale + k0 + kk + 4);
                    const float4 h0 = *(const float4*)(a_shift + k0 + kk);
                    const float4 h1 = *(const float4*)(a_shift + k0 + kk + 4);
                    ab[0] = f2bf(fmaxf(0.f, bf2f(ab[0]) * s0.x + h0.x));
                    ab[1] = f2bf(fmaxf(0.f, bf2f(ab[1]) * s0.y + h0.y));
                    ab[2] = f2bf(fmaxf(0.f, bf2f(ab[2]) * s0.z + h0.z));
                    ab[3] = f2bf(fmaxf(0.f, bf2f(ab[3]) * s0.w + h0.w));
                    ab[4] = f2bf(fmaxf(0.f, bf2f(ab[4]) * s1.x + h1.x));
                    ab[5] = f2bf(fmaxf(0.f, bf2f(ab[5]) * s1.y + h1.y));
                    ab[6] = f2bf(fmaxf(0.f, bf2f(ab[6]) * s1.z + h1.z));
                    ab[7] = f2bf(fmaxf(0.f, bf2f(ab[7]) * s1.w + h1.w));
                }
            }
            *(float4*)&As[r * 40 + kk] = av;
            float4 bv = *(const float4*)(Bt + (size_t)(bn + r) * K + k0 + kk);
            *(float4*)&Bs[r * 40 + kk] = bv;
        }
        __syncthreads();
        short8 af[4], bfr[4];
#pragma unroll
        for (int i = 0; i < 4; ++i)
            af[i] = *(const short8*)&As[(wm + i * 16 + lm) * 40 + quad * 8];
#pragma unroll
        for (int j = 0; j < 4; ++j)
            bfr[j] = *(const short8*)&Bs[(wn + j * 16 + lm) * 40 + quad * 8];
#pragma unroll
        for (int i = 0; i < 4; ++i)
#pragma unroll
            for (int j = 0; j < 4; ++j)
                acc[i][j] = __builtin_amdgcn_mfma_f32_16x16x32_bf16(af[i], bfr[j], acc[i][j], 0, 0, 0);
        __syncthreads();
    }

#pragma unroll
    for (int j = 0; j < 4; ++j) {
        int col = bn + wn + j * 16 + lm;
        float bj = bias[col];
        float s = 0.f, q = 0.f;
#pragma unroll
        for (int i = 0; i < 4; ++i) {
            int row0 = bm + wm + i * 16 + quad * 4;
#pragma unroll
            for (int r = 0; r < 4; ++r) {
                int row = row0 + r;
                float x = acc[i][j][r] + bj;
                if (row < M) {
                    s += x; q += x * x;
                    if (OUT_BF16) ((u16*)Cout)[(size_t)row * Ncols + col] = f2bf(x);
                    else          ((float*)Cout)[(size_t)row * Ncols + col] = x;
                }
            }
        }
        s += __shfl_xor(s, 16); q += __shfl_xor(q, 16);
        s += __shfl_xor(s, 32); q += __shfl_xor(q, 32);
        if (quad == 0) {
            atomicAdd(&sum[col], s);
            atomicAdd(&sumsq[col], q);
        }
    }
}

// ---------------- BN finalize ----------------
__global__ void bn_finalize_kernel(const float* __restrict__ sum, const float* __restrict__ sumsq,
                                   const float* __restrict__ gamma, const float* __restrict__ beta,
                                   float* __restrict__ scale, float* __restrict__ shift,
                                   float inv_n) {
    int c = threadIdx.x;
    float m = sum[c] * inv_n;
    float var = sumsq[c] * inv_n - m * m;
    float rs = rsqrtf(var + 1e-5f);
    float sc = gamma[c] * rs;
    scale[c] = sc;
    shift[c] = beta[c] - sc * m;
}

// ---------------- BN apply + ReLU fp32 in-place (final output) ----------------
__global__ void bn_apply_relu_kernel(float* __restrict__ X,
                                     const float* __restrict__ scale,
                                     const float* __restrict__ shift,
                                     int n4, int c4mask) {
    int i = blockIdx.x * blockDim.x + threadIdx.x;
    if (i >= n4) return;
    int c = (i & c4mask) << 2;
    float4 x = ((const float4*)X)[i];
    float4 sc = *(const float4*)(scale + c);
    float4 sh = *(const float4*)(shift + c);
    float4 y;
    y.x = fmaxf(0.f, x.x * sc.x + sh.x);
    y.y = fmaxf(0.f, x.y * sc.y + sh.y);
    y.z = fmaxf(0.f, x.z * sc.z + sh.z);
    y.w = fmaxf(0.f, x.w * sc.w + sh.w);
    ((float4*)X)[i] = y;
}

extern "C" void kernel_launch(void* const* d_in, const int* in_sizes, int n_in,
                              void* d_out, int out_size, void* d_ws, size_t ws_size,
                              hipStream_t stream) {
    const float* v    = (const float*)d_in[0];
    const int* src    = (const int*)d_in[1];
    const int* dst    = (const int*)d_in[2];
    const float* ew   = (const float*)d_in[3];
    const float* eps  = (const float*)d_in[4];
    const float* W1   = (const float*)d_in[5];
    const float* b1   = (const float*)d_in[6];
    const float* g1   = (const float*)d_in[7];
    const float* be1  = (const float*)d_in[8];
    const float* W2   = (const float*)d_in[9];
    const float* b2   = (const float*)d_in[10];
    const float* g2   = (const float*)d_in[11];
    const float* be2  = (const float*)d_in[12];
    float* out = (float*)d_out;

    // ---- workspace layout (bytes) ----
    char* base = (char*)d_ws;
    u16* x1   = (u16*)(base);                      // [N,512] bf16  = 51,200,000 B
    u16* vbf  = (u16*)(base + 51200000ull);        // [N,128] bf16  = 12,800,000 B
    u16* vagg = (u16*)(base + 64000000ull);        // [N,128] bf16  = 12,800,000 B
    u16* W1t  = (u16*)(base + 76800000ull);        // 128*512 bf16
    u16* W2t  = (u16*)(base + 76931072ull);        // 128*512 bf16
    float* sum1   = (float*)(base + 77062144ull);
    float* sumsq1 = sum1 + 512;
    float* sum2   = sumsq1 + 512;
    float* sumsq2 = sum2 + 128;
    float* scale1 = sumsq2 + 128;
    float* shift1 = scale1 + 512;
    float* scale2 = shift1 + 512;
    float* shift2 = scale2 + 128;
    int* counts     = (int*)(shift2 + 128);
    int* cursor     = counts + 50000;
    int* row_start  = cursor + 50000;              // 50001 (+pad 3)
    int2* csr_ew    = (int2*)(row_start + 50004);  // 800,000 * 8 B
    int* block_sums = (int*)(csr_ew + 800000);     // 256
    int* block_offs = block_sums + 256;            // 256

    // zero: stats + scale/shift + counts + cursor
    hipMemsetAsync(sum1, 0, (size_t)(1280 + 1280 + 100000) * sizeof(float), stream);

    // CSR build + casts
    hist_kernel<<<(E_EDGES + 255) / 256, 256, 0, stream>>>(dst, counts);
    reduce_kernel<<<SCAN_NB, 256, 0, stream>>>(counts, block_sums);
    scan_block_sums<<<1, 256, 0, stream>>>(block_sums, block_offs);
    scan_final<<<SCAN_NB, 256, 0, stream>>>(counts, block_offs, row_start);
    fill_kernel<<<(E_EDGES + 255) / 256, 256, 0, stream>>>(src, dst, ew, row_start, cursor, csr_ew);
    cast_v_kernel<<<(N_NODES * D_INF / 8 + 255) / 256, 256, 0, stream>>>(v, vbf);
    prep_weights_kernel<<<(128 * 512 + 255) / 256, 256, 0, stream>>>(W1, W2, W1t, W2t);
    gather_kernel<<<(N_NODES + 7) / 8, 256, 0, stream>>>(vbf, row_start, csr_ew, eps, vagg);

    // GEMM1 + BN1 stats: x1 = vagg @ W1 + b1 (bf16 out, raw pre-BN)
    {
        dim3 grid(D_HIDF / 128, (N_NODES + 127) / 128);
        mfma_gemm_bn<1, 0><<<grid, 256, 0, stream>>>(vagg, W1t, b1, nullptr, nullptr,
                                                     x1, sum1, sumsq1, N_NODES, D_HIDF, D_INF);
    }
    bn_finalize_kernel<<<1, D_HIDF, 0, stream>>>(sum1, sumsq1, g1, be1, scale1, shift1,
                                                 1.0f / N_NODES);
    // GEMM2 + BN2 stats: out_raw = relu(bn1(x1)) @ W2 + b2 — BN1 applied in A-staging
    {
        dim3 grid(D_OUTF / 128, (N_NODES + 127) / 128);
        mfma_gemm_bn<0, 1><<<grid, 256, 0, stream>>>(x1, W2t, b2, scale1, shift1,
                                                     out, sum2, sumsq2, N_NODES, D_OUTF, D_HIDF);
    }
    bn_finalize_kernel<<<1, D_OUTF, 0, stream>>>(sum2, sumsq2, g2, be2, scale2, shift2,
                                                 1.0f / N_NODES);
    // BN2 apply + ReLU in-place on d_out
    {
        int n4 = N_NODES * D_OUTF / 4;
        bn_apply_relu_kernel<<<(n4 + 255) / 256, 256, 0, stream>>>(out, scale2, shift2, n4, 31);
    }
}